// Round 1
// baseline (6107.371 us; speedup 1.0000x reference)
//
#include <hip/hip_runtime.h>
#include <hip/hip_bf16.h>

typedef __hip_bfloat16 bf16;

#define HH 256
#define WW 256
#define BB 8
#define SS 1024
#define PD 147

static const long N_FEAT    = 134217728L;   // 8*256*256*256
static const long OFF_PREAL = 134217728L;
static const long OFF_PRECON= 135421952L;
static const long OFF_WA    = 136626176L;
static const long OFF_WP    = 138723328L;

__device__ __forceinline__ float lrelu(float v){ return v >= 0.f ? v : 0.01f*v; }

__device__ __forceinline__ unsigned short f2bf(float f){
    __hip_bfloat16 h = __float2bfloat16(f);
    return *reinterpret_cast<unsigned short*>(&h);
}

// ---------------------------------------------------------------------------
// Direct 3x3 SAME conv. 32x32 output tile per block, KB=32 output channels,
// each thread computes 4 consecutive x-pixels. Input channel staged in LDS
// (with optional inline BN+LeakyReLU of the previous layer's raw output).
// ---------------------------------------------------------------------------
template<int C_IN, int K_OUT, bool IN_BF16, bool BN_IN, bool OUT_BF16>
__global__ __launch_bounds__(256)
void conv3x3(const void* __restrict__ in_, const float* __restrict__ wgt,
             const float* __restrict__ ss, void* __restrict__ out_)
{
    constexpr int KB = 32;
    __shared__ float tile[34][36];

    const int gx = blockIdx.x;          // 0..63 (8x8 tiles)
    const int bx = (gx & 7) * 32;
    const int by = (gx >> 3) * 32;
    const int b  = blockIdx.y;
    const int k0 = blockIdx.z * KB;
    const int tid = threadIdx.x;
    const int ty = tid >> 3;            // 0..31
    const int tx = (tid & 7) * 4;       // 0,4,...,28

    float acc[KB][4];
#pragma unroll
    for (int k = 0; k < KB; k++){ acc[k][0]=0.f; acc[k][1]=0.f; acc[k][2]=0.f; acc[k][3]=0.f; }

    const float* inF = (const float*)in_;
    const bf16*  inB = (const bf16*)in_;

#pragma unroll 1
    for (int c = 0; c < C_IN; c++){
        float sc = 1.f, sh = 0.f;
        if (BN_IN){ sc = ss[c]; sh = ss[C_IN + c]; }
        const long cbase = ((long)(b*C_IN + c)) << 16;
        for (int i = tid; i < 34*34; i += 256){
            const int ry = i / 34, rx = i - ry*34;
            const int gy = by + ry - 1, gxx = bx + rx - 1;
            float v = 0.f;
            if ((unsigned)gy < 256u && (unsigned)gxx < 256u){
                const long idx = cbase + ((long)gy << 8) + gxx;
                v = IN_BF16 ? __bfloat162float(inB[idx]) : inF[idx];
                if (BN_IN) v = lrelu(sc*v + sh);
            }
            tile[ry][rx] = v;
        }
        __syncthreads();

        float seg[3][6];
#pragma unroll
        for (int dy = 0; dy < 3; dy++){
            const float* r = &tile[ty+dy][tx];
#pragma unroll
            for (int j = 0; j < 6; j++) seg[dy][j] = r[j];
        }

        const float* wc = wgt + (long)(k0*C_IN + c)*9;
#pragma unroll
        for (int k = 0; k < KB; k++){
            const float* wk = wc + (long)k*C_IN*9;
#pragma unroll
            for (int dy = 0; dy < 3; dy++){
#pragma unroll
                for (int dx = 0; dx < 3; dx++){
                    const float wv = wk[dy*3 + dx];
                    acc[k][0] += seg[dy][dx+0]*wv;
                    acc[k][1] += seg[dy][dx+1]*wv;
                    acc[k][2] += seg[dy][dx+2]*wv;
                    acc[k][3] += seg[dy][dx+3]*wv;
                }
            }
        }
        __syncthreads();
    }

    const int gyo = by + ty, gxo = bx + tx;
#pragma unroll
    for (int k = 0; k < KB; k++){
        const int co = k0 + k;
        const long obase = (((long)(b*K_OUT + co)) << 16) + ((long)gyo << 8) + gxo;
        if (OUT_BF16){
            ushort4 u;
            u.x = f2bf(acc[k][0]); u.y = f2bf(acc[k][1]);
            u.z = f2bf(acc[k][2]); u.w = f2bf(acc[k][3]);
            *reinterpret_cast<ushort4*>((bf16*)out_ + obase) = u;
        } else {
            float4 v = make_float4(acc[k][0], acc[k][1], acc[k][2], acc[k][3]);
            *reinterpret_cast<float4*>((float*)out_ + obase) = v;
        }
    }
}

// ---------------------------------------------------------------------------
// BN stats: deterministic two-stage reduction. Stage 1: grid (C, 64) partials.
// ---------------------------------------------------------------------------
template<bool BF16IN>
__global__ __launch_bounds__(256)
void bn_stats_partial(const void* __restrict__ f, int C, float* __restrict__ part)
{
    const int c = blockIdx.x, j = blockIdx.y;   // j 0..63
    const int bimg = j >> 3, p = j & 7;
    const long base = (((long)(bimg*C + c)) << 16) + (long)p*8192;
    float s = 0.f, s2 = 0.f;
    for (int t = threadIdx.x; t < 8192; t += 256){
        float v = BF16IN ? __bfloat162float(((const bf16*)f)[base + t])
                         : ((const float*)f)[base + t];
        s += v; s2 += v*v;
    }
    __shared__ float r0[256], r1[256];
    r0[threadIdx.x] = s; r1[threadIdx.x] = s2;
    __syncthreads();
    for (int st = 128; st > 0; st >>= 1){
        if ((int)threadIdx.x < st){
            r0[threadIdx.x] += r0[threadIdx.x + st];
            r1[threadIdx.x] += r1[threadIdx.x + st];
        }
        __syncthreads();
    }
    if (threadIdx.x == 0){
        part[(c*64 + j)*2]     = r0[0];
        part[(c*64 + j)*2 + 1] = r1[0];
    }
}

__global__ __launch_bounds__(64)
void bn_stats_final(const float* __restrict__ part, const float* __restrict__ g,
                    const float* __restrict__ bb, int C, float* __restrict__ ss)
{
    const int c = blockIdx.x;
    const int t = threadIdx.x;
    __shared__ float r0[64], r1[64];
    r0[t] = part[(c*64 + t)*2];
    r1[t] = part[(c*64 + t)*2 + 1];
    __syncthreads();
    for (int st = 32; st > 0; st >>= 1){
        if (t < st){ r0[t] += r0[t+st]; r1[t] += r1[t+st]; }
        __syncthreads();
    }
    if (t == 0){
        const float invN = 1.f / 524288.f;
        const float m   = r0[0] * invN;
        const float var = r1[0] * invN - m*m;
        const float sc  = g[c] / sqrtf(var + 1e-5f);
        ss[c]     = sc;
        ss[C + c] = bb[c] - m*sc;
    }
}

// normalize+lrelu layer-4 output in place (it is the `feat` output)
__global__ __launch_bounds__(256)
void bn_finalize(float* __restrict__ feat, const float* __restrict__ ss)
{
    const long e4 = (long)blockIdx.x*256 + threadIdx.x;   // float4 index
    const int c = (int)((e4 >> 14) & 255);
    const float sc = ss[c], sh = ss[256 + c];
    float4 v = reinterpret_cast<float4*>(feat)[e4];
    v.x = lrelu(sc*v.x + sh); v.y = lrelu(sc*v.y + sh);
    v.z = lrelu(sc*v.z + sh); v.w = lrelu(sc*v.w + sh);
    reinterpret_cast<float4*>(feat)[e4] = v;
}

// gather feat[b, :, y, x] -> out[b, s, :]
__global__ __launch_bounds__(256)
void gather_w(const float* __restrict__ feat, const int* __restrict__ hw,
              float* __restrict__ outW)
{
    const int site = blockIdx.x;            // 0..8191
    const int b = site >> 10;
    const int y = hw[site*2], x = hw[site*2 + 1];
    const int c = threadIdx.x;              // 0..255
    const long fidx = (((long)(b*256 + c)) << 16) + ((long)y << 8) + x;
    outW[(long)site*256 + c] = feat[fidx];
}

// gather 7x7x3 patches of x around anchors
__global__ __launch_bounds__(256)
void gather_patch(const float* __restrict__ x, const int* __restrict__ hw,
                  float* __restrict__ out)
{
    const long i = (long)blockIdx.x*256 + threadIdx.x;
    if (i >= 1204224L) return;
    const int px = (int)(i % 7);
    long r = i / 7;
    const int py = (int)(r % 7); r /= 7;
    const int c  = (int)(r % 3); r /= 3;
    const int s  = (int)(r % 1024);
    const int b  = (int)(r / 1024);
    const int site = b*1024 + s;
    const int yy = hw[site*2]     - 3 + py;
    const int xx = hw[site*2 + 1] - 3 + px;
    out[i] = x[(((long)(b*3 + c)) << 16) + ((long)yy << 8) + xx];
}

// patch decoder MLP: h = lrelu(Wa @ l1w^T + b1); recon = h @ l2w^T + b2
__global__ __launch_bounds__(256)
void mlp(const float* __restrict__ Wa, const float* __restrict__ l1w,
         const float* __restrict__ l1b, const float* __restrict__ l2w,
         const float* __restrict__ l2b, float* __restrict__ out)
{
    __shared__ float wa[256];
    __shared__ float h[160];
    const int site = blockIdx.x;
    const int t = threadIdx.x;
    wa[t] = Wa[(long)site*256 + t];
    __syncthreads();
    if (t < PD){
        float a = l1b[t];
        const float* wr = l1w + t*256;
#pragma unroll 8
        for (int l = 0; l < 256; l++) a += wa[l]*wr[l];
        h[t] = lrelu(a);
    }
    __syncthreads();
    if (t < PD){
        float a = l2b[t];
        const float* wr = l2w + t*PD;
        for (int p = 0; p < PD; p++) a += h[p]*wr[p];
        out[(long)site*PD + t] = a;
    }
}

extern "C" void kernel_launch(void* const* d_in, const int* in_sizes, int n_in,
                              void* d_out, int out_size, void* d_ws, size_t ws_size,
                              hipStream_t stream)
{
    const float* x      = (const float*)d_in[0];
    const int*   anc    = (const int*)  d_in[1];
    const int*   pos    = (const int*)  d_in[2];
    const float* w1     = (const float*)d_in[3];
    const float* g1     = (const float*)d_in[4];
    const float* b1     = (const float*)d_in[5];
    const float* w2     = (const float*)d_in[6];
    const float* g2     = (const float*)d_in[7];
    const float* b2     = (const float*)d_in[8];
    const float* w3     = (const float*)d_in[9];
    const float* g3     = (const float*)d_in[10];
    const float* b3     = (const float*)d_in[11];
    const float* w4     = (const float*)d_in[12];
    const float* g4     = (const float*)d_in[13];
    const float* b4     = (const float*)d_in[14];
    const float* l1w    = (const float*)d_in[15];
    const float* l1b    = (const float*)d_in[16];
    const float* l2w    = (const float*)d_in[17];
    const float* l2b    = (const float*)d_in[18];

    float* feat = (float*)d_out;                       // raw then normalized in place
    float* oPR  = (float*)d_out + OFF_PREAL;
    float* oRC  = (float*)d_out + OFF_PRECON;
    float* oWA  = (float*)d_out + OFF_WA;
    float* oWP  = (float*)d_out + OFF_WP;

    char* w = (char*)d_ws;
    bf16*  f13  = (bf16*)w;                            // f1 (33.5MB) then f3 (134MB)
    bf16*  f2   = (bf16*)(w + 134217728L);             // 67MB
    float* part = (float*)(w + 201326592L);            // 256*64*2 floats
    float* ss1  = (float*)(w + 201457664L);
    float* ss2  = ss1 + 64;
    float* ss3  = ss2 + 128;
    float* ss4  = ss3 + 256;

    dim3 blk(256);

    // layer 1: x fp32 -> raw f1 bf16
    conv3x3<3, 32, false, false, true><<<dim3(64, BB, 1), blk, 0, stream>>>(x, w1, nullptr, f13);
    bn_stats_partial<true><<<dim3(32, 64), blk, 0, stream>>>(f13, 32, part);
    bn_stats_final<<<dim3(32), dim3(64), 0, stream>>>(part, g1, b1, 32, ss1);

    // layer 2: f1 (BN+lrelu inline) -> raw f2
    conv3x3<32, 64, true, true, true><<<dim3(64, BB, 2), blk, 0, stream>>>(f13, w2, ss1, f2);
    bn_stats_partial<true><<<dim3(64, 64), blk, 0, stream>>>(f2, 64, part);
    bn_stats_final<<<dim3(64), dim3(64), 0, stream>>>(part, g2, b2, 64, ss2);

    // layer 3: f2 -> raw f3 (overwrites f1 space; f1 dead)
    conv3x3<64, 128, true, true, true><<<dim3(64, BB, 4), blk, 0, stream>>>(f2, w3, ss2, f13);
    bn_stats_partial<true><<<dim3(128, 64), blk, 0, stream>>>(f13, 128, part);
    bn_stats_final<<<dim3(128), dim3(64), 0, stream>>>(part, g3, b3, 128, ss3);

    // layer 4: f3 -> raw f4 fp32 straight into d_out feat region
    conv3x3<128, 256, true, true, false><<<dim3(64, BB, 8), blk, 0, stream>>>(f13, w4, ss3, feat);
    bn_stats_partial<false><<<dim3(256, 64), blk, 0, stream>>>(feat, 256, part);
    bn_stats_final<<<dim3(256), dim3(64), 0, stream>>>(part, g4, b4, 256, ss4);

    // normalize + lrelu in place -> final feat
    bn_finalize<<<dim3(131072), blk, 0, stream>>>(feat, ss4);

    // gathers
    gather_w<<<dim3(8192), blk, 0, stream>>>(feat, anc, oWA);
    gather_w<<<dim3(8192), blk, 0, stream>>>(feat, pos, oWP);
    gather_patch<<<dim3(4704), blk, 0, stream>>>(x, anc, oPR);

    // patch decoder
    mlp<<<dim3(8192), blk, 0, stream>>>(oWA, l1w, l1b, l2w, l2b, oRC);
}

// Round 2
// 4068.741 us; speedup vs baseline: 1.5010x; 1.5010x over previous
//
#include <hip/hip_runtime.h>
#include <hip/hip_bf16.h>

typedef unsigned short u16;
typedef short bf16x8 __attribute__((ext_vector_type(8)));
typedef float f32x4 __attribute__((ext_vector_type(4)));
typedef unsigned short u16x8 __attribute__((ext_vector_type(8)));

#define PD 147

static const long OFF_PREAL = 134217728L;
static const long OFF_PRECON= 135421952L;
static const long OFF_WA    = 136626176L;
static const long OFF_WP    = 138723328L;

__device__ __forceinline__ float lrelu(float v){ return v >= 0.f ? v : 0.01f*v; }

__device__ __forceinline__ float bf2f(u16 u){
    union { unsigned int i; float f; } x; x.i = ((unsigned int)u) << 16; return x.f;
}
__device__ __forceinline__ u16 f2bf(float f){
    __hip_bfloat16 h = __float2bfloat16(f);
    return *reinterpret_cast<u16*>(&h);
}

__device__ __forceinline__ void gload16(const void* g, void* l){
    __builtin_amdgcn_global_load_lds((const __attribute__((address_space(1))) void*)g,
                                     (__attribute__((address_space(3))) void*)l, 16, 0, 0);
}

// ---------------------------------------------------------------------------
// MFMA implicit-GEMM 3x3 SAME conv.  16x16 spatial tile x all K_OUT channels
// per block.  8 waves (2M x 4N).  Input NHWC bf16 (pre-activated), weights
// pre-transposed [tap][k_out][c_in] bf16.  Output: NHWC bf16 raw, or (conv4)
// NCHW fp32 raw via LDS-transpose epilogue.
// ---------------------------------------------------------------------------
template<int CIN, int KOUT, bool NCHW_OUT>
__global__ __launch_bounds__(512)
void conv_mfma(const u16* __restrict__ fin, const u16* __restrict__ wt, void* __restrict__ out_)
{
    constexpr int CC = CIN / 32;
    constexpr int NSTEPS = CC * 9;
    constexpr int NF = KOUT / 64;
    constexpr int ABYTES = 2 * 324 * 32 * 2;          // double-buffered 18x18x32 bf16
    constexpr int BBYTES = 2 * KOUT * 32 * 2;
    constexpr int EPIB = NCHW_OUT ? (8 * 2112 * 4) : (256 * KOUT * 2);
    constexpr int SB = (ABYTES + BBYTES) > EPIB ? (ABYTES + BBYTES) : EPIB;
    __shared__ __align__(16) char smem[SB];
    u16* As = (u16*)smem;
    u16* Bs = (u16*)(smem + ABYTES);

    const int tid = threadIdx.x;
    const int w = tid >> 6, lane = tid & 63;
    const int wm = w >> 2, wn = w & 3;
    const int tile = blockIdx.x;
    const int tx0 = (tile & 15) << 4, ty0 = (tile >> 4) << 4;
    const int b = blockIdx.y;
    const long pixbase = (long)b << 16;

    f32x4 acc[8][NF];
#pragma unroll
    for (int m = 0; m < 8; m++)
#pragma unroll
        for (int n = 0; n < NF; n++) acc[m][n] = (f32x4){0.f,0.f,0.f,0.f};

    // zero A buffers once (boundary rows rely on staying zero)
    for (int i = tid; i < ABYTES/16; i += 512)
        ((int4*)smem)[i] = make_int4(0,0,0,0);
    __syncthreads();

    auto stage_a = [&](int cc, int buf){
        u16* dstbase = As + buf * (324*32);
#pragma unroll
        for (int r = 0; r < 3; ++r){
            int q = r*512 + w*64 + lane;
            int pf = q >> 2, quarter = q & 3;
            int ly = pf / 18;
            int lx = pf - ly*18;
            int gy = ty0 + ly - 1, gx = tx0 + lx - 1;
            bool ok = (q < 1296) && ((unsigned)gy < 256u) && ((unsigned)gx < 256u);
            const u16* src = fin + ((pixbase + (gy<<8) + gx) * CIN + cc*32 + quarter*8);
            u16* dst = dstbase + (r*512 + w*64) * 8;
            if (ok) gload16(src, dst);
        }
    };
    auto stage_b = [&](int cc, int tap, int buf){
        u16* dstbase = Bs + buf * (KOUT*32);
        constexpr int BCH = KOUT * 4;
#pragma unroll
        for (int r = 0; r < (BCH + 511)/512; ++r){
            int q = r*512 + w*64 + lane;
            int k = q >> 2, quarter = q & 3;
            const u16* src = wt + (((long)tap*KOUT + k) * CIN + cc*32 + quarter*8);
            u16* dst = dstbase + (r*512 + w*64) * 8;
            if (q < BCH) gload16(src, dst);
        }
    };

    stage_a(0, 0);
    stage_b(0, 0, 0);

#pragma unroll 1
    for (int step = 0; step < NSTEPS; ++step){
        int cc = step / 9, tap = step - cc*9;
        int nxt = step + 1;
        if (nxt < NSTEPS){
            int ncc = nxt / 9, ntap = nxt - ncc*9;
            if (ntap == 0) stage_a(ncc, ncc & 1);
            stage_b(ncc, ntap, nxt & 1);
        }
        __syncthreads();                       // staging (incl. prefetch) drained
        const u16* Ab = As + (cc & 1) * (324*32);
        const u16* Bb = Bs + (step & 1) * (KOUT*32);
        int dy = tap / 3, dx = tap - dy*3;
        bf16x8 av[8];
#pragma unroll
        for (int m = 0; m < 8; m++){
            int pf = (wm*8 + m + dy)*18 + (lane & 15) + dx;
            av[m] = *(const bf16x8*)(Ab + pf*32 + (lane>>4)*8);
        }
        bf16x8 bv[NF];
#pragma unroll
        for (int n = 0; n < NF; n++){
            int ch = (wn*NF + n)*16 + (lane & 15);
            bv[n] = *(const bf16x8*)(Bb + ch*32 + (lane>>4)*8);
        }
#pragma unroll
        for (int m = 0; m < 8; m++)
#pragma unroll
            for (int n = 0; n < NF; n++)
                acc[m][n] = __builtin_amdgcn_mfma_f32_16x16x32_bf16(av[m], bv[n], acc[m][n], 0, 0, 0);
        __syncthreads();                       // readers done before next overwrite
    }

    if constexpr (NCHW_OUT){
        // per-wave LDS transpose -> fp32 NCHW (raw, pre-BN)
        float* ep = (float*)smem + w*2112;
        float* outf = (float*)out_;
#pragma unroll 1
        for (int nf = 0; nf < NF; ++nf){
#pragma unroll
            for (int m = 0; m < 8; m++)
#pragma unroll
                for (int j = 0; j < 4; j++)
                    ep[(lane&15)*132 + m*16 + (lane>>4)*4 + j] = acc[m][nf][j];
#pragma unroll
            for (int k2 = 0; k2 < 8; k2++){
                int flat = k2*64 + lane;
                int ch = flat >> 5, fmr = (flat>>2)&7, quad = flat & 3;
                float4 v = *(float4*)&ep[ch*132 + fmr*16 + quad*4];
                int cg = wn*(NF*16) + nf*16 + ch;
                long addr = ((long)((b<<8) + cg) << 16) + ((ty0 + wm*8 + fmr) << 8) + tx0 + quad*4;
                *(float4*)(outf + addr) = v;
            }
        }
    } else {
        // block-wide LDS transpose -> NHWC bf16 raw, fully coalesced stores
        u16* ep = (u16*)smem;
        u16* outh = (u16*)out_;
#pragma unroll
        for (int m = 0; m < 8; m++)
#pragma unroll
            for (int n = 0; n < NF; n++){
                int ch = (wn*NF + n)*16 + (lane&15);
#pragma unroll
                for (int j = 0; j < 4; j++){
                    int px = wm*128 + m*16 + (lane>>4)*4 + j;
                    ep[px*KOUT + ch] = f2bf(acc[m][n][j]);
                }
            }
        __syncthreads();
        const int n16 = 256*KOUT/8;
        const int upr = KOUT*2;                 // 16B units per spatial row
        for (int i = tid; i < n16; i += 512){
            int py = i / upr;
            int rem = i - py*upr;
            long ga = (pixbase + ((ty0+py)<<8) + tx0) * KOUT + (long)rem*8;
            *(int4*)(outh + ga) = *(int4*)(ep + (long)i*8);
        }
    }
}

// ---------------------------------------------------------------------------
// conv1: 3->32 direct (tiny), output NHWC bf16 raw
// ---------------------------------------------------------------------------
__global__ __launch_bounds__(256)
void conv1_direct(const float* __restrict__ x, const float* __restrict__ w1, u16* __restrict__ f1)
{
    __shared__ float wl[864];
    const int t = threadIdx.x;
    for (int i = t; i < 864; i += 256) wl[i] = w1[i];
    __syncthreads();
    const int y = blockIdx.x, b = blockIdx.y;
    float acc[32];
#pragma unroll
    for (int k = 0; k < 32; k++) acc[k] = 0.f;
    const long ib = (long)b*3*65536;
    for (int c = 0; c < 3; c++){
#pragma unroll
        for (int dy = 0; dy < 3; dy++){
            int gy = y + dy - 1;
#pragma unroll
            for (int dx = 0; dx < 3; dx++){
                int gx = t + dx - 1;
                float v = 0.f;
                if ((unsigned)gy < 256u && (unsigned)gx < 256u)
                    v = x[ib + c*65536 + (gy<<8) + gx];
                const float* wp = &wl[c*9 + dy*3 + dx];
#pragma unroll
                for (int k = 0; k < 32; k++) acc[k] += v * wp[k*27];
            }
        }
    }
    u16 ub[32];
#pragma unroll
    for (int k = 0; k < 32; k++) ub[k] = f2bf(acc[k]);
    u16* dst = f1 + ((long)(b*65536 + (y<<8) + t)) * 32;
#pragma unroll
    for (int j = 0; j < 4; j++) *(int4*)(dst + j*8) = *(int4*)(ub + j*8);
}

// weight transpose: wt[tap][k][c] = bf16(w[k][c][tap])
__global__ __launch_bounds__(256)
void prep_w(const float* __restrict__ w, u16* __restrict__ wt, int K, int C)
{
    int i = blockIdx.x*256 + threadIdx.x;
    if (i >= 9*K*C) return;
    int c = i % C; int r = i / C; int k = r % K; int tap = r / K;
    wt[i] = f2bf(w[((long)k*C + c)*9 + tap]);
}

// ---------------------------------------------------------------------------
// BN stats over NHWC bf16: stage 1 partials (deterministic), NB=1024 blocks
// ---------------------------------------------------------------------------
template<int C>
__global__ __launch_bounds__(256)
void bn_stats_nhwc(const u16* __restrict__ f, float* __restrict__ part)
{
    constexpr int CQ = C/4;
    constexpr int SUBS = 256/CQ;
    const int t = threadIdx.x;
    const int cq = t & (CQ-1);
    const int sub = t / CQ;
    const long rowbase = (long)blockIdx.x * 512;
    float s[4] = {0,0,0,0}, q2[4] = {0,0,0,0};
    for (int r = sub; r < 512; r += SUBS){
        ushort4 v = *(const ushort4*)(f + (rowbase + r)*C + cq*4);
        float x0 = bf2f(v.x), x1 = bf2f(v.y), x2 = bf2f(v.z), x3 = bf2f(v.w);
        s[0]+=x0; q2[0]+=x0*x0; s[1]+=x1; q2[1]+=x1*x1;
        s[2]+=x2; q2[2]+=x2*x2; s[3]+=x3; q2[3]+=x3*x3;
    }
    __shared__ float r0[256], r1[256];
    for (int j = 0; j < 4; j++){
        r0[t] = s[j]; r1[t] = q2[j];
        __syncthreads();
        for (int st = 128; st >= CQ; st >>= 1){
            if (t < st){ r0[t] += r0[t+st]; r1[t] += r1[t+st]; }
            __syncthreads();
        }
        if (t < CQ){
            part[((long)blockIdx.x * C + t*4 + j)*2]     = r0[t];
            part[((long)blockIdx.x * C + t*4 + j)*2 + 1] = r1[t];
        }
        __syncthreads();
    }
}

__global__ __launch_bounds__(256)
void bn_stats_final2(const float* __restrict__ part, const float* __restrict__ g,
                     const float* __restrict__ bb, int C, int NB, float* __restrict__ ss)
{
    const int c = blockIdx.x, t = threadIdx.x;
    float s = 0.f, s2 = 0.f;
    for (int i = t; i < NB; i += 256){
        s  += part[((long)i*C + c)*2];
        s2 += part[((long)i*C + c)*2 + 1];
    }
    __shared__ float r0[256], r1[256];
    r0[t] = s; r1[t] = s2;
    __syncthreads();
    for (int st = 128; st > 0; st >>= 1){
        if (t < st){ r0[t] += r0[t+st]; r1[t] += r1[t+st]; }
        __syncthreads();
    }
    if (t == 0){
        const float invN = 1.f/524288.f;
        float m = r0[0]*invN;
        float v = r1[0]*invN - m*m;
        float sc = g[c]/sqrtf(v + 1e-5f);
        ss[c] = sc; ss[C+c] = bb[c] - m*sc;
    }
}

// apply BN+lrelu in place on NHWC bf16
template<int C>
__global__ __launch_bounds__(256)
void bn_apply(u16* __restrict__ f, const float* __restrict__ ss, long n8)
{
    long i = (long)blockIdx.x*256 + threadIdx.x;
    if (i >= n8) return;
    u16x8 v = *(u16x8*)(f + i*8);
    int c0 = (int)((i*8) & (C-1));
#pragma unroll
    for (int j = 0; j < 8; j++){
        float xx = bf2f(v[j]);
        xx = lrelu(ss[c0+j]*xx + ss[C+c0+j]);
        v[j] = f2bf(xx);
    }
    *(u16x8*)(f + i*8) = v;
}

// ---------------------------------------------------------------------------
// f4 (fp32 NCHW) stats + finalize — proven round-1 kernels
// ---------------------------------------------------------------------------
__global__ __launch_bounds__(256)
void bn_stats_partial_f32(const float* __restrict__ f, int C, float* __restrict__ part)
{
    const int c = blockIdx.x, j = blockIdx.y;
    const int bimg = j >> 3, p = j & 7;
    const long base = (((long)(bimg*C + c)) << 16) + (long)p*8192;
    float s = 0.f, s2 = 0.f;
    for (int t = threadIdx.x; t < 8192; t += 256){
        float v = f[base + t];
        s += v; s2 += v*v;
    }
    __shared__ float r0[256], r1[256];
    r0[threadIdx.x] = s; r1[threadIdx.x] = s2;
    __syncthreads();
    for (int st = 128; st > 0; st >>= 1){
        if ((int)threadIdx.x < st){
            r0[threadIdx.x] += r0[threadIdx.x + st];
            r1[threadIdx.x] += r1[threadIdx.x + st];
        }
        __syncthreads();
    }
    if (threadIdx.x == 0){
        part[(c*64 + j)*2]     = r0[0];
        part[(c*64 + j)*2 + 1] = r1[0];
    }
}

__global__ __launch_bounds__(64)
void bn_stats_final(const float* __restrict__ part, const float* __restrict__ g,
                    const float* __restrict__ bb, int C, float* __restrict__ ss)
{
    const int c = blockIdx.x;
    const int t = threadIdx.x;
    __shared__ float r0[64], r1[64];
    r0[t] = part[(c*64 + t)*2];
    r1[t] = part[(c*64 + t)*2 + 1];
    __syncthreads();
    for (int st = 32; st > 0; st >>= 1){
        if (t < st){ r0[t] += r0[t+st]; r1[t] += r1[t+st]; }
        __syncthreads();
    }
    if (t == 0){
        const float invN = 1.f / 524288.f;
        const float m   = r0[0] * invN;
        const float var = r1[0] * invN - m*m;
        const float sc  = g[c] / sqrtf(var + 1e-5f);
        ss[c]     = sc;
        ss[C + c] = bb[c] - m*sc;
    }
}

__global__ __launch_bounds__(256)
void bn_finalize(float* __restrict__ feat, const float* __restrict__ ss)
{
    const long e4 = (long)blockIdx.x*256 + threadIdx.x;
    const int c = (int)((e4 >> 14) & 255);
    const float sc = ss[c], sh = ss[256 + c];
    float4 v = reinterpret_cast<float4*>(feat)[e4];
    v.x = lrelu(sc*v.x + sh); v.y = lrelu(sc*v.y + sh);
    v.z = lrelu(sc*v.z + sh); v.w = lrelu(sc*v.w + sh);
    reinterpret_cast<float4*>(feat)[e4] = v;
}

// ---------------------------------------------------------------------------
// gathers + decoder MLP — proven round-1 kernels
// ---------------------------------------------------------------------------
__global__ __launch_bounds__(256)
void gather_w(const float* __restrict__ feat, const int* __restrict__ hw,
              float* __restrict__ outW)
{
    const int site = blockIdx.x;
    const int b = site >> 10;
    const int y = hw[site*2], x = hw[site*2 + 1];
    const int c = threadIdx.x;
    const long fidx = (((long)(b*256 + c)) << 16) + ((long)y << 8) + x;
    outW[(long)site*256 + c] = feat[fidx];
}

__global__ __launch_bounds__(256)
void gather_patch(const float* __restrict__ x, const int* __restrict__ hw,
                  float* __restrict__ out)
{
    const long i = (long)blockIdx.x*256 + threadIdx.x;
    if (i >= 1204224L) return;
    const int px = (int)(i % 7);
    long r = i / 7;
    const int py = (int)(r % 7); r /= 7;
    const int c  = (int)(r % 3); r /= 3;
    const int s  = (int)(r % 1024);
    const int b  = (int)(r / 1024);
    const int site = b*1024 + s;
    const int yy = hw[site*2]     - 3 + py;
    const int xx = hw[site*2 + 1] - 3 + px;
    out[i] = x[(((long)(b*3 + c)) << 16) + ((long)yy << 8) + xx];
}

__global__ __launch_bounds__(256)
void mlp(const float* __restrict__ Wa, const float* __restrict__ l1w,
         const float* __restrict__ l1b, const float* __restrict__ l2w,
         const float* __restrict__ l2b, float* __restrict__ out)
{
    __shared__ float wa[256];
    __shared__ float h[160];
    const int site = blockIdx.x;
    const int t = threadIdx.x;
    wa[t] = Wa[(long)site*256 + t];
    __syncthreads();
    if (t < PD){
        float a = l1b[t];
        const float* wr = l1w + t*256;
#pragma unroll 8
        for (int l = 0; l < 256; l++) a += wa[l]*wr[l];
        h[t] = lrelu(a);
    }
    __syncthreads();
    if (t < PD){
        float a = l2b[t];
        const float* wr = l2w + t*PD;
        for (int p = 0; p < PD; p++) a += h[p]*wr[p];
        out[(long)site*PD + t] = a;
    }
}

extern "C" void kernel_launch(void* const* d_in, const int* in_sizes, int n_in,
                              void* d_out, int out_size, void* d_ws, size_t ws_size,
                              hipStream_t stream)
{
    const float* x   = (const float*)d_in[0];
    const int*   anc = (const int*)  d_in[1];
    const int*   pos = (const int*)  d_in[2];
    const float* w1  = (const float*)d_in[3];
    const float* g1  = (const float*)d_in[4];
    const float* b1  = (const float*)d_in[5];
    const float* w2  = (const float*)d_in[6];
    const float* g2  = (const float*)d_in[7];
    const float* b2  = (const float*)d_in[8];
    const float* w3  = (const float*)d_in[9];
    const float* g3  = (const float*)d_in[10];
    const float* b3  = (const float*)d_in[11];
    const float* w4  = (const float*)d_in[12];
    const float* g4  = (const float*)d_in[13];
    const float* b4  = (const float*)d_in[14];
    const float* l1w = (const float*)d_in[15];
    const float* l1b = (const float*)d_in[16];
    const float* l2w = (const float*)d_in[17];
    const float* l2b = (const float*)d_in[18];

    float* feat = (float*)d_out;
    float* oPR  = feat + OFF_PREAL;
    float* oRC  = feat + OFF_PRECON;
    float* oWA  = feat + OFF_WA;
    float* oWP  = feat + OFF_WP;

    // ws: f2 [0,64MB), f3 [64MB,192MB), f1 [128MB,160MB) (inside f3, dead before conv3)
    char* wsb = (char*)d_ws;
    u16* f2b = (u16*)wsb;
    u16* f3b = (u16*)(wsb + 67108864L);
    u16* f1b = (u16*)(wsb + 134217728L);

    // scratch inside d_out regions that are only written by the final kernels
    u16* Wt2 = (u16*)oWA;
    u16* Wt3 = Wt2 + 18432;
    u16* Wt4 = Wt3 + 73728;
    float* part = oWP;
    float* ss1 = oRC, *ss2 = oRC + 64, *ss3 = oRC + 192, *ss4 = oRC + 448;

    prep_w<<<72,   256, 0, stream>>>(w2, Wt2, 64, 32);
    prep_w<<<288,  256, 0, stream>>>(w3, Wt3, 128, 64);
    prep_w<<<1152, 256, 0, stream>>>(w4, Wt4, 256, 128);

    conv1_direct<<<dim3(256,8), 256, 0, stream>>>(x, w1, f1b);
    bn_stats_nhwc<32><<<1024, 256, 0, stream>>>(f1b, part);
    bn_stats_final2<<<32, 256, 0, stream>>>(part, g1, b1, 32, 1024, ss1);
    bn_apply<32><<<8192, 256, 0, stream>>>(f1b, ss1, 2097152L);

    conv_mfma<32,64,false><<<dim3(256,8), 512, 0, stream>>>(f1b, Wt2, f2b);
    bn_stats_nhwc<64><<<1024, 256, 0, stream>>>(f2b, part);
    bn_stats_final2<<<64, 256, 0, stream>>>(part, g2, b2, 64, 1024, ss2);
    bn_apply<64><<<16384, 256, 0, stream>>>(f2b, ss2, 4194304L);

    conv_mfma<64,128,false><<<dim3(256,8), 512, 0, stream>>>(f2b, Wt3, f3b);
    bn_stats_nhwc<128><<<1024, 256, 0, stream>>>(f3b, part);
    bn_stats_final2<<<128, 256, 0, stream>>>(part, g3, b3, 128, 1024, ss3);
    bn_apply<128><<<32768, 256, 0, stream>>>(f3b, ss3, 8388608L);

    conv_mfma<128,256,true><<<dim3(256,8), 512, 0, stream>>>(f3b, Wt4, feat);
    bn_stats_partial_f32<<<dim3(256,64), 256, 0, stream>>>(feat, 256, part);
    bn_stats_final<<<256, 64, 0, stream>>>(part, g4, b4, 256, ss4);
    bn_finalize<<<131072, 256, 0, stream>>>(feat, ss4);

    gather_w<<<8192, 256, 0, stream>>>(feat, anc, oWA);
    gather_w<<<8192, 256, 0, stream>>>(feat, pos, oWP);
    gather_patch<<<4704, 256, 0, stream>>>(x, anc, oPR);
    mlp<<<8192, 256, 0, stream>>>(oWA, l1w, l1b, l2w, l2b, oRC);
}

// Round 3
// 1292.651 us; speedup vs baseline: 4.7247x; 3.1476x over previous
//
#include <hip/hip_runtime.h>
#include <hip/hip_bf16.h>

typedef unsigned short u16;
typedef short bf16x8 __attribute__((ext_vector_type(8)));
typedef float f32x4 __attribute__((ext_vector_type(4)));
typedef unsigned short u16x8 __attribute__((ext_vector_type(8)));

#define PD 147

static const long OFF_PREAL = 134217728L;
static const long OFF_PRECON= 135421952L;
static const long OFF_WA    = 136626176L;
static const long OFF_WP    = 138723328L;

__device__ __forceinline__ float lrelu(float v){ return v >= 0.f ? v : 0.01f*v; }

__device__ __forceinline__ float bf2f(u16 u){
    union { unsigned int i; float f; } x; x.i = ((unsigned int)u) << 16; return x.f;
}
__device__ __forceinline__ u16 f2bf(float f){
    __hip_bfloat16 h = __float2bfloat16(f);
    return *reinterpret_cast<u16*>(&h);
}

__device__ __forceinline__ void gload16(const void* g, void* l){
    __builtin_amdgcn_global_load_lds((const __attribute__((address_space(1))) void*)g,
                                     (__attribute__((address_space(3))) void*)l, 16, 0, 0);
}

// ---------------------------------------------------------------------------
// MFMA implicit-GEMM 3x3 SAME conv.  16x16 spatial tile x all K_OUT channels
// per block.  8 waves (2M x 4N).  Input NHWC bf16 (pre-activated), weights
// pre-transposed [tap][k_out][c_in] bf16.  Output: NHWC bf16 raw, or (conv4)
// NCHW fp32 raw via LDS-transpose epilogue.  Fused deterministic BN partial
// stats (pre-rounding fp32) into part[(bid*2+wm)*KOUT + ch].
// ---------------------------------------------------------------------------
template<int CIN, int KOUT, bool NCHW_OUT>
__global__ __launch_bounds__(512)
void conv_mfma(const u16* __restrict__ fin, const u16* __restrict__ wt,
               void* __restrict__ out_, float* __restrict__ part)
{
    constexpr int CC = CIN / 32;
    constexpr int NSTEPS = CC * 9;
    constexpr int NF = KOUT / 64;
    constexpr int ABYTES = 2 * 324 * 32 * 2;          // double-buffered 18x18x32 bf16
    constexpr int BBYTES = 2 * KOUT * 32 * 2;
    constexpr int EPIB = NCHW_OUT ? (8 * 2112 * 4) : (256 * KOUT * 2);
    constexpr int SB = (ABYTES + BBYTES) > EPIB ? (ABYTES + BBYTES) : EPIB;
    __shared__ __align__(16) char smem[SB];
    u16* As = (u16*)smem;
    u16* Bs = (u16*)(smem + ABYTES);

    const int tid = threadIdx.x;
    const int w = tid >> 6, lane = tid & 63;
    const int wm = w >> 2, wn = w & 3;
    const int tile = blockIdx.x;
    const int tx0 = (tile & 15) << 4, ty0 = (tile >> 4) << 4;
    const int b = blockIdx.y;
    const long pixbase = (long)b << 16;

    f32x4 acc[8][NF];
#pragma unroll
    for (int m = 0; m < 8; m++)
#pragma unroll
        for (int n = 0; n < NF; n++) acc[m][n] = (f32x4){0.f,0.f,0.f,0.f};

    // zero A buffers once (boundary rows rely on staying zero)
    for (int i = tid; i < ABYTES/16; i += 512)
        ((int4*)smem)[i] = make_int4(0,0,0,0);
    __syncthreads();

    auto stage_a = [&](int cc, int buf){
        u16* dstbase = As + buf * (324*32);
#pragma unroll
        for (int r = 0; r < 3; ++r){
            int q = r*512 + w*64 + lane;
            int pf = q >> 2, quarter = q & 3;
            int ly = pf / 18;
            int lx = pf - ly*18;
            int gy = ty0 + ly - 1, gx = tx0 + lx - 1;
            bool ok = (q < 1296) && ((unsigned)gy < 256u) && ((unsigned)gx < 256u);
            const u16* src = fin + ((pixbase + (gy<<8) + gx) * CIN + cc*32 + quarter*8);
            u16* dst = dstbase + (r*512 + w*64) * 8;
            if (ok) gload16(src, dst);
        }
    };
    auto stage_b = [&](int cc, int tap, int buf){
        u16* dstbase = Bs + buf * (KOUT*32);
        constexpr int BCH = KOUT * 4;
#pragma unroll
        for (int r = 0; r < (BCH + 511)/512; ++r){
            int q = r*512 + w*64 + lane;
            int k = q >> 2, quarter = q & 3;
            const u16* src = wt + (((long)tap*KOUT + k) * CIN + cc*32 + quarter*8);
            u16* dst = dstbase + (r*512 + w*64) * 8;
            if (q < BCH) gload16(src, dst);
        }
    };

    stage_a(0, 0);
    stage_b(0, 0, 0);

#pragma unroll 1
    for (int step = 0; step < NSTEPS; ++step){
        int cc = step / 9, tap = step - cc*9;
        int nxt = step + 1;
        if (nxt < NSTEPS){
            int ncc = nxt / 9, ntap = nxt - ncc*9;
            if (ntap == 0) stage_a(ncc, ncc & 1);
            stage_b(ncc, ntap, nxt & 1);
        }
        __syncthreads();                       // staging (incl. prefetch) drained
        const u16* Ab = As + (cc & 1) * (324*32);
        const u16* Bb = Bs + (step & 1) * (KOUT*32);
        int dy = tap / 3, dx = tap - dy*3;
        bf16x8 av[8];
#pragma unroll
        for (int m = 0; m < 8; m++){
            int pf = (wm*8 + m + dy)*18 + (lane & 15) + dx;
            av[m] = *(const bf16x8*)(Ab + pf*32 + (lane>>4)*8);
        }
        bf16x8 bv[NF];
#pragma unroll
        for (int n = 0; n < NF; n++){
            int ch = (wn*NF + n)*16 + (lane & 15);
            bv[n] = *(const bf16x8*)(Bb + ch*32 + (lane>>4)*8);
        }
#pragma unroll
        for (int m = 0; m < 8; m++)
#pragma unroll
            for (int n = 0; n < NF; n++)
                acc[m][n] = __builtin_amdgcn_mfma_f32_16x16x32_bf16(av[m], bv[n], acc[m][n], 0, 0, 0);
        __syncthreads();                       // readers done before next overwrite
    }

    // ---- fused BN partial stats (fp32, pre-rounding), deterministic slots ----
    {
        const int bid = blockIdx.y * 256 + blockIdx.x;
        const long slot = (long)bid * 2 + wm;
#pragma unroll
        for (int n = 0; n < NF; n++){
            float s = 0.f, s2 = 0.f;
#pragma unroll
            for (int m = 0; m < 8; m++)
#pragma unroll
                for (int j = 0; j < 4; j++){
                    float v = acc[m][n][j];
                    s += v; s2 += v*v;
                }
            s += __shfl_down(s, 32); s2 += __shfl_down(s2, 32);
            s += __shfl_down(s, 16); s2 += __shfl_down(s2, 16);
            if (lane < 16){
                int ch = (wn*NF + n)*16 + lane;
                long off = (slot*KOUT + ch)*2;
                part[off]   = s;
                part[off+1] = s2;
            }
        }
    }

    if constexpr (NCHW_OUT){
        // per-wave LDS transpose -> fp32 NCHW (raw, pre-BN); fully unrolled
        float* ep = (float*)smem + w*2112;
        float* outf = (float*)out_;
#pragma unroll
        for (int nf = 0; nf < NF; ++nf){
#pragma unroll
            for (int m = 0; m < 8; m++)
#pragma unroll
                for (int j = 0; j < 4; j++)
                    ep[(lane&15)*132 + m*16 + (lane>>4)*4 + j] = acc[m][nf][j];
#pragma unroll
            for (int k2 = 0; k2 < 8; k2++){
                int flat = k2*64 + lane;
                int ch = flat >> 5, fmr = (flat>>2)&7, quad = flat & 3;
                float4 v = *(float4*)&ep[ch*132 + fmr*16 + quad*4];
                int cg = wn*(NF*16) + nf*16 + ch;
                long addr = ((long)((b<<8) + cg) << 16) + ((ty0 + wm*8 + fmr) << 8) + tx0 + quad*4;
                *(float4*)(outf + addr) = v;
            }
        }
    } else {
        // block-wide LDS transpose -> NHWC bf16 raw, fully coalesced stores
        u16* ep = (u16*)smem;
        u16* outh = (u16*)out_;
#pragma unroll
        for (int m = 0; m < 8; m++)
#pragma unroll
            for (int n = 0; n < NF; n++){
                int ch = (wn*NF + n)*16 + (lane&15);
#pragma unroll
                for (int j = 0; j < 4; j++){
                    int px = wm*128 + m*16 + (lane>>4)*4 + j;
                    ep[px*KOUT + ch] = f2bf(acc[m][n][j]);
                }
            }
        __syncthreads();
        const int n16 = 256*KOUT/8;
        const int upr = KOUT*2;                 // 16B units per spatial row
        for (int i = tid; i < n16; i += 512){
            int py = i / upr;
            int rem = i - py*upr;
            long ga = (pixbase + ((ty0+py)<<8) + tx0) * KOUT + (long)rem*8;
            *(int4*)(outh + ga) = *(int4*)(ep + (long)i*8);
        }
    }
}

// ---------------------------------------------------------------------------
// conv1: 3->32 direct (tiny), output NHWC bf16 raw
// ---------------------------------------------------------------------------
__global__ __launch_bounds__(256)
void conv1_direct(const float* __restrict__ x, const float* __restrict__ w1, u16* __restrict__ f1)
{
    __shared__ float wl[864];
    const int t = threadIdx.x;
    for (int i = t; i < 864; i += 256) wl[i] = w1[i];
    __syncthreads();
    const int y = blockIdx.x, b = blockIdx.y;
    float acc[32];
#pragma unroll
    for (int k = 0; k < 32; k++) acc[k] = 0.f;
    const long ib = (long)b*3*65536;
    for (int c = 0; c < 3; c++){
#pragma unroll
        for (int dy = 0; dy < 3; dy++){
            int gy = y + dy - 1;
#pragma unroll
            for (int dx = 0; dx < 3; dx++){
                int gx = t + dx - 1;
                float v = 0.f;
                if ((unsigned)gy < 256u && (unsigned)gx < 256u)
                    v = x[ib + c*65536 + (gy<<8) + gx];
                const float* wp = &wl[c*9 + dy*3 + dx];
#pragma unroll
                for (int k = 0; k < 32; k++) acc[k] += v * wp[k*27];
            }
        }
    }
    u16 ub[32];
#pragma unroll
    for (int k = 0; k < 32; k++) ub[k] = f2bf(acc[k]);
    u16* dst = f1 + ((long)(b*65536 + (y<<8) + t)) * 32;
#pragma unroll
    for (int j = 0; j < 4; j++) *(int4*)(dst + j*8) = *(int4*)(ub + j*8);
}

// weight transpose: wt[tap][k][c] = bf16(w[k][c][tap])
__global__ __launch_bounds__(256)
void prep_w(const float* __restrict__ w, u16* __restrict__ wt, int K, int C)
{
    int i = blockIdx.x*256 + threadIdx.x;
    if (i >= 9*K*C) return;
    int c = i % C; int r = i / C; int k = r % K; int tap = r / K;
    wt[i] = f2bf(w[((long)k*C + c)*9 + tap]);
}

// ---------------------------------------------------------------------------
// BN stats over NHWC bf16 (layer 1 only)
// ---------------------------------------------------------------------------
template<int C>
__global__ __launch_bounds__(256)
void bn_stats_nhwc(const u16* __restrict__ f, float* __restrict__ part)
{
    constexpr int CQ = C/4;
    constexpr int SUBS = 256/CQ;
    const int t = threadIdx.x;
    const int cq = t & (CQ-1);
    const int sub = t / CQ;
    const long rowbase = (long)blockIdx.x * 512;
    float s[4] = {0,0,0,0}, q2[4] = {0,0,0,0};
    for (int r = sub; r < 512; r += SUBS){
        ushort4 v = *(const ushort4*)(f + (rowbase + r)*C + cq*4);
        float x0 = bf2f(v.x), x1 = bf2f(v.y), x2 = bf2f(v.z), x3 = bf2f(v.w);
        s[0]+=x0; q2[0]+=x0*x0; s[1]+=x1; q2[1]+=x1*x1;
        s[2]+=x2; q2[2]+=x2*x2; s[3]+=x3; q2[3]+=x3*x3;
    }
    __shared__ float r0[256], r1[256];
    for (int j = 0; j < 4; j++){
        r0[t] = s[j]; r1[t] = q2[j];
        __syncthreads();
        for (int st = 128; st >= CQ; st >>= 1){
            if (t < st){ r0[t] += r0[t+st]; r1[t] += r1[t+st]; }
            __syncthreads();
        }
        if (t < CQ){
            part[((long)blockIdx.x * C + t*4 + j)*2]     = r0[t];
            part[((long)blockIdx.x * C + t*4 + j)*2 + 1] = r1[t];
        }
        __syncthreads();
    }
}

__global__ __launch_bounds__(256)
void bn_stats_final2(const float* __restrict__ part, const float* __restrict__ g,
                     const float* __restrict__ bb, int C, int NB, float* __restrict__ ss)
{
    const int c = blockIdx.x, t = threadIdx.x;
    float s = 0.f, s2 = 0.f;
    for (int i = t; i < NB; i += 256){
        s  += part[((long)i*C + c)*2];
        s2 += part[((long)i*C + c)*2 + 1];
    }
    __shared__ float r0[256], r1[256];
    r0[t] = s; r1[t] = s2;
    __syncthreads();
    for (int st = 128; st > 0; st >>= 1){
        if (t < st){ r0[t] += r0[t+st]; r1[t] += r1[t+st]; }
        __syncthreads();
    }
    if (t == 0){
        const float invN = 1.f/524288.f;
        float m = r0[0]*invN;
        float v = r1[0]*invN - m*m;
        float sc = g[c]/sqrtf(v + 1e-5f);
        ss[c] = sc; ss[C+c] = bb[c] - m*sc;
    }
}

// apply BN+lrelu in place on NHWC bf16
template<int C>
__global__ __launch_bounds__(256)
void bn_apply(u16* __restrict__ f, const float* __restrict__ ss, long n8)
{
    long i = (long)blockIdx.x*256 + threadIdx.x;
    if (i >= n8) return;
    u16x8 v = *(u16x8*)(f + i*8);
    int c0 = (int)((i*8) & (C-1));
#pragma unroll
    for (int j = 0; j < 8; j++){
        float xx = bf2f(v[j]);
        xx = lrelu(ss[c0+j]*xx + ss[C+c0+j]);
        v[j] = f2bf(xx);
    }
    *(u16x8*)(f + i*8) = v;
}

// normalize + lrelu layer-4 fp32 NCHW in place
__global__ __launch_bounds__(256)
void bn_finalize(float* __restrict__ feat, const float* __restrict__ ss)
{
    const long e4 = (long)blockIdx.x*256 + threadIdx.x;
    const int c = (int)((e4 >> 14) & 255);
    const float sc = ss[c], sh = ss[256 + c];
    float4 v = reinterpret_cast<float4*>(feat)[e4];
    v.x = lrelu(sc*v.x + sh); v.y = lrelu(sc*v.y + sh);
    v.z = lrelu(sc*v.z + sh); v.w = lrelu(sc*v.w + sh);
    reinterpret_cast<float4*>(feat)[e4] = v;
}

// ---------------------------------------------------------------------------
// gathers + decoder MLP
// ---------------------------------------------------------------------------
__global__ __launch_bounds__(256)
void gather_w(const float* __restrict__ feat, const int* __restrict__ hw,
              float* __restrict__ outW)
{
    const int site = blockIdx.x;
    const int b = site >> 10;
    const int y = hw[site*2], x = hw[site*2 + 1];
    const int c = threadIdx.x;
    const long fidx = (((long)(b*256 + c)) << 16) + ((long)y << 8) + x;
    outW[(long)site*256 + c] = feat[fidx];
}

__global__ __launch_bounds__(256)
void gather_patch(const float* __restrict__ x, const int* __restrict__ hw,
                  float* __restrict__ out)
{
    const long i = (long)blockIdx.x*256 + threadIdx.x;
    if (i >= 1204224L) return;
    const int px = (int)(i % 7);
    long r = i / 7;
    const int py = (int)(r % 7); r /= 7;
    const int c  = (int)(r % 3); r /= 3;
    const int s  = (int)(r % 1024);
    const int b  = (int)(r / 1024);
    const int site = b*1024 + s;
    const int yy = hw[site*2]     - 3 + py;
    const int xx = hw[site*2 + 1] - 3 + px;
    out[i] = x[(((long)(b*3 + c)) << 16) + ((long)yy << 8) + xx];
}

__global__ __launch_bounds__(256)
void mlp(const float* __restrict__ Wa, const float* __restrict__ l1w,
         const float* __restrict__ l1b, const float* __restrict__ l2w,
         const float* __restrict__ l2b, float* __restrict__ out)
{
    __shared__ float wa[256];
    __shared__ float h[160];
    const int site = blockIdx.x;
    const int t = threadIdx.x;
    wa[t] = Wa[(long)site*256 + t];
    __syncthreads();
    if (t < PD){
        float a = l1b[t];
        const float* wr = l1w + t*256;
#pragma unroll 8
        for (int l = 0; l < 256; l++) a += wa[l]*wr[l];
        h[t] = lrelu(a);
    }
    __syncthreads();
    if (t < PD){
        float a = l2b[t];
        const float* wr = l2w + t*PD;
        for (int p = 0; p < PD; p++) a += h[p]*wr[p];
        out[(long)site*PD + t] = a;
    }
}

extern "C" void kernel_launch(void* const* d_in, const int* in_sizes, int n_in,
                              void* d_out, int out_size, void* d_ws, size_t ws_size,
                              hipStream_t stream)
{
    const float* x   = (const float*)d_in[0];
    const int*   anc = (const int*)  d_in[1];
    const int*   pos = (const int*)  d_in[2];
    const float* w1  = (const float*)d_in[3];
    const float* g1  = (const float*)d_in[4];
    const float* b1  = (const float*)d_in[5];
    const float* w2  = (const float*)d_in[6];
    const float* g2  = (const float*)d_in[7];
    const float* b2  = (const float*)d_in[8];
    const float* w3  = (const float*)d_in[9];
    const float* g3  = (const float*)d_in[10];
    const float* b3  = (const float*)d_in[11];
    const float* w4  = (const float*)d_in[12];
    const float* g4  = (const float*)d_in[13];
    const float* b4  = (const float*)d_in[14];
    const float* l1w = (const float*)d_in[15];
    const float* l1b = (const float*)d_in[16];
    const float* l2w = (const float*)d_in[17];
    const float* l2b = (const float*)d_in[18];

    float* feat = (float*)d_out;
    float* oPR  = feat + OFF_PREAL;
    float* oRC  = feat + OFF_PRECON;
    float* oWA  = feat + OFF_WA;
    float* oWP  = feat + OFF_WP;

    // ws: f2 [0,64MB), f3 [64MB,192MB), f1 [128MB,160MB) (inside f3, dead before conv3)
    char* wsb = (char*)d_ws;
    u16* f2b = (u16*)wsb;
    u16* f3b = (u16*)(wsb + 67108864L);
    u16* f1b = (u16*)(wsb + 134217728L);

    // scratch inside d_out regions only written by the final kernels
    u16* Wt2 = (u16*)oWA;
    u16* Wt3 = Wt2 + 18432;
    u16* Wt4 = Wt3 + 73728;
    float* part = oWP;                                   // 4096*256*2 floats max
    float* ss1 = oRC, *ss2 = oRC + 64, *ss3 = oRC + 192, *ss4 = oRC + 448;

    prep_w<<<72,   256, 0, stream>>>(w2, Wt2, 64, 32);
    prep_w<<<288,  256, 0, stream>>>(w3, Wt3, 128, 64);
    prep_w<<<1152, 256, 0, stream>>>(w4, Wt4, 256, 128);

    conv1_direct<<<dim3(256,8), 256, 0, stream>>>(x, w1, f1b);
    bn_stats_nhwc<32><<<1024, 256, 0, stream>>>(f1b, part);
    bn_stats_final2<<<32, 256, 0, stream>>>(part, g1, b1, 32, 1024, ss1);
    bn_apply<32><<<8192, 256, 0, stream>>>(f1b, ss1, 2097152L);

    conv_mfma<32,64,false><<<dim3(256,8), 512, 0, stream>>>(f1b, Wt2, f2b, part);
    bn_stats_final2<<<64, 256, 0, stream>>>(part, g2, b2, 64, 4096, ss2);
    bn_apply<64><<<16384, 256, 0, stream>>>(f2b, ss2, 4194304L);

    conv_mfma<64,128,false><<<dim3(256,8), 512, 0, stream>>>(f2b, Wt3, f3b, part);
    bn_stats_final2<<<128, 256, 0, stream>>>(part, g3, b3, 128, 4096, ss3);
    bn_apply<128><<<32768, 256, 0, stream>>>(f3b, ss3, 8388608L);

    conv_mfma<128,256,true><<<dim3(256,8), 512, 0, stream>>>(f3b, Wt4, feat, part);
    bn_stats_final2<<<256, 256, 0, stream>>>(part, g4, b4, 256, 4096, ss4);
    bn_finalize<<<131072, 256, 0, stream>>>(feat, ss4);

    gather_w<<<8192, 256, 0, stream>>>(feat, anc, oWA);
    gather_w<<<8192, 256, 0, stream>>>(feat, pos, oWP);
    gather_patch<<<4704, 256, 0, stream>>>(x, anc, oPR);
    mlp<<<8192, 256, 0, stream>>>(oWA, l1w, l1b, l2w, l2b, oRC);
}

// Round 4
// 1225.192 us; speedup vs baseline: 4.9848x; 1.0551x over previous
//
#include <hip/hip_runtime.h>
#include <hip/hip_bf16.h>

typedef unsigned short u16;
typedef short bf16x8 __attribute__((ext_vector_type(8)));
typedef float f32x4 __attribute__((ext_vector_type(4)));
typedef unsigned short u16x8 __attribute__((ext_vector_type(8)));

#define PD 147

static const long OFF_PREAL = 134217728L;
static const long OFF_PRECON= 135421952L;
static const long OFF_WA    = 136626176L;
static const long OFF_WP    = 138723328L;

__device__ __forceinline__ float lrelu(float v){ return v >= 0.f ? v : 0.01f*v; }

__device__ __forceinline__ float bf2f(u16 u){
    union { unsigned int i; float f; } x; x.i = ((unsigned int)u) << 16; return x.f;
}
__device__ __forceinline__ u16 f2bf(float f){
    __hip_bfloat16 h = __float2bfloat16(f);
    return *reinterpret_cast<u16*>(&h);
}

__device__ __forceinline__ void gload16(const void* g, void* l){
    __builtin_amdgcn_global_load_lds((const __attribute__((address_space(1))) void*)g,
                                     (__attribute__((address_space(3))) void*)l, 16, 0, 0);
}

// ---------------------------------------------------------------------------
// MFMA implicit-GEMM 3x3 SAME conv.  16x16 spatial tile x all K_OUT channels
// per block.  8 waves (2M x 4N).  Input NHWC bf16 (pre-activated), weights
// pre-transposed [tap][k_out][c_in] bf16.
//
// Pipeline: single barrier per K-step (T3 minimum 2-phase): issue next-step
// gload_lds BEFORE compute(cur); one vmcnt(0)+barrier at step end.
// LDS swizzle (rule #21, both-sides): 16B quarter ^= (row&3) applied to the
// GLOBAL source (dest stays linear for gload_lds) and to the ds_read offset.
// Fused deterministic BN partial stats into part[(bid*2+wm)*KOUT + ch].
// ---------------------------------------------------------------------------
template<int CIN, int KOUT, bool NCHW_OUT>
__global__ __launch_bounds__(512)
void conv_mfma(const u16* __restrict__ fin, const u16* __restrict__ wt,
               void* __restrict__ out_, float* __restrict__ part)
{
    constexpr int CC = CIN / 32;
    constexpr int NSTEPS = CC * 9;
    constexpr int NF = KOUT / 64;
    constexpr int ABYTES = 2 * 324 * 32 * 2;          // double-buffered 18x18x32 bf16
    constexpr int BBYTES = 2 * KOUT * 32 * 2;
    constexpr int EPIB = NCHW_OUT ? (8 * 2112 * 4) : (256 * KOUT * 2);
    constexpr int SB = (ABYTES + BBYTES) > EPIB ? (ABYTES + BBYTES) : EPIB;
    __shared__ __align__(16) char smem[SB];
    u16* As = (u16*)smem;
    u16* Bs = (u16*)(smem + ABYTES);

    const int tid = threadIdx.x;
    const int w = tid >> 6, lane = tid & 63;
    const int wm = w >> 2, wn = w & 3;
    const int tile = blockIdx.x;
    const int tx0 = (tile & 15) << 4, ty0 = (tile >> 4) << 4;
    const int b = blockIdx.y;
    const long pixbase = (long)b << 16;
    const int hi = lane >> 4;

    f32x4 acc[8][NF];
#pragma unroll
    for (int m = 0; m < 8; m++)
#pragma unroll
        for (int n = 0; n < NF; n++) acc[m][n] = (f32x4){0.f,0.f,0.f,0.f};

    // zero A buffers once (boundary rows rely on staying zero)
    for (int i = tid; i < ABYTES/16; i += 512)
        ((int4*)smem)[i] = make_int4(0,0,0,0);
    __syncthreads();

    auto stage_a = [&](int cc, int buf){
        u16* dstbase = As + buf * (324*32);
#pragma unroll
        for (int r = 0; r < 3; ++r){
            int q = r*512 + w*64 + lane;
            int pf = q >> 2, quarter = q & 3;
            int qs = quarter ^ (pf & 3);            // swizzled source quarter
            int ly = pf / 18;
            int lx = pf - ly*18;
            int gy = ty0 + ly - 1, gx = tx0 + lx - 1;
            bool ok = (q < 1296) && ((unsigned)gy < 256u) && ((unsigned)gx < 256u);
            const u16* src = fin + ((pixbase + (gy<<8) + gx) * CIN + cc*32 + qs*8);
            u16* dst = dstbase + (r*512 + w*64) * 8;
            if (ok) gload16(src, dst);
        }
    };
    auto stage_b = [&](int cc, int tap, int buf){
        u16* dstbase = Bs + buf * (KOUT*32);
        constexpr int BCH = KOUT * 4;
#pragma unroll
        for (int r = 0; r < (BCH + 511)/512; ++r){
            int q = r*512 + w*64 + lane;
            int k = q >> 2, quarter = q & 3;
            int qs = quarter ^ (k & 3);             // swizzled source quarter
            const u16* src = wt + (((long)tap*KOUT + k) * CIN + cc*32 + qs*8);
            u16* dst = dstbase + (r*512 + w*64) * 8;
            if (q < BCH) gload16(src, dst);
        }
    };

    stage_a(0, 0);
    stage_b(0, 0, 0);
    __syncthreads();

#pragma unroll 1
    for (int step = 0; step < NSTEPS; ++step){
        int cc = step / 9, tap = step - cc*9;
        int nxt = step + 1;
        if (nxt < NSTEPS){
            int ncc = nxt / 9, ntap = nxt - ncc*9;
            if (ntap == 0) stage_a(ncc, ncc & 1);
            stage_b(ncc, ntap, nxt & 1);
        }
        const u16* Ab = As + (cc & 1) * (324*32);
        const u16* Bb = Bs + (step & 1) * (KOUT*32);
        int dy = tap / 3, dx = tap - dy*3;
        bf16x8 av[8];
#pragma unroll
        for (int m = 0; m < 8; m++){
            int pf = (wm*8 + m + dy)*18 + (lane & 15) + dx;
            av[m] = *(const bf16x8*)(Ab + pf*32 + ((hi ^ (pf & 3)) * 8));
        }
        bf16x8 bv[NF];
#pragma unroll
        for (int n = 0; n < NF; n++){
            int ch = (wn*NF + n)*16 + (lane & 15);
            bv[n] = *(const bf16x8*)(Bb + ch*32 + ((hi ^ (ch & 3)) * 8));
        }
#pragma unroll
        for (int m = 0; m < 8; m++)
#pragma unroll
            for (int n = 0; n < NF; n++)
                acc[m][n] = __builtin_amdgcn_mfma_f32_16x16x32_bf16(av[m], bv[n], acc[m][n], 0, 0, 0);
        __syncthreads();   // drains vmcnt (next bufs ready) + readers done
    }

    // ---- fused BN partial stats (fp32, pre-rounding), deterministic slots ----
    {
        const int bid = blockIdx.y * 256 + blockIdx.x;
        const long slot = (long)bid * 2 + wm;
#pragma unroll
        for (int n = 0; n < NF; n++){
            float s = 0.f, s2 = 0.f;
#pragma unroll
            for (int m = 0; m < 8; m++)
#pragma unroll
                for (int j = 0; j < 4; j++){
                    float v = acc[m][n][j];
                    s += v; s2 += v*v;
                }
            s += __shfl_down(s, 32); s2 += __shfl_down(s2, 32);
            s += __shfl_down(s, 16); s2 += __shfl_down(s2, 16);
            if (lane < 16){
                int ch = (wn*NF + n)*16 + lane;
                long off = (slot*KOUT + ch)*2;
                part[off]   = s;
                part[off+1] = s2;
            }
        }
    }

    if constexpr (NCHW_OUT){
        // per-wave LDS transpose -> fp32 NCHW (raw, pre-BN); fully unrolled
        float* ep = (float*)smem + w*2112;
        float* outf = (float*)out_;
#pragma unroll
        for (int nf = 0; nf < NF; ++nf){
#pragma unroll
            for (int m = 0; m < 8; m++)
#pragma unroll
                for (int j = 0; j < 4; j++)
                    ep[(lane&15)*132 + m*16 + (lane>>4)*4 + j] = acc[m][nf][j];
#pragma unroll
            for (int k2 = 0; k2 < 8; k2++){
                int flat = k2*64 + lane;
                int ch = flat >> 5, fmr = (flat>>2)&7, quad = flat & 3;
                float4 v = *(float4*)&ep[ch*132 + fmr*16 + quad*4];
                int cg = wn*(NF*16) + nf*16 + ch;
                long addr = ((long)((b<<8) + cg) << 16) + ((ty0 + wm*8 + fmr) << 8) + tx0 + quad*4;
                *(float4*)(outf + addr) = v;
            }
        }
    } else {
        // block-wide LDS transpose -> NHWC bf16 raw, fully coalesced stores
        u16* ep = (u16*)smem;
        u16* outh = (u16*)out_;
#pragma unroll
        for (int m = 0; m < 8; m++)
#pragma unroll
            for (int n = 0; n < NF; n++){
                int ch = (wn*NF + n)*16 + (lane&15);
#pragma unroll
                for (int j = 0; j < 4; j++){
                    int px = wm*128 + m*16 + (lane>>4)*4 + j;
                    ep[px*KOUT + ch] = f2bf(acc[m][n][j]);
                }
            }
        __syncthreads();
        const int n16 = 256*KOUT/8;
        const int upr = KOUT*2;                 // 16B units per spatial row
        for (int i = tid; i < n16; i += 512){
            int py = i / upr;
            int rem = i - py*upr;
            long ga = (pixbase + ((ty0+py)<<8) + tx0) * KOUT + (long)rem*8;
            *(int4*)(outh + ga) = *(int4*)(ep + (long)i*8);
        }
    }
}

// ---------------------------------------------------------------------------
// conv1: 3->32 direct (tiny), output NHWC bf16 raw
// ---------------------------------------------------------------------------
__global__ __launch_bounds__(256)
void conv1_direct(const float* __restrict__ x, const float* __restrict__ w1, u16* __restrict__ f1)
{
    __shared__ float wl[864];
    const int t = threadIdx.x;
    for (int i = t; i < 864; i += 256) wl[i] = w1[i];
    __syncthreads();
    const int y = blockIdx.x, b = blockIdx.y;
    float acc[32];
#pragma unroll
    for (int k = 0; k < 32; k++) acc[k] = 0.f;
    const long ib = (long)b*3*65536;
    for (int c = 0; c < 3; c++){
#pragma unroll
        for (int dy = 0; dy < 3; dy++){
            int gy = y + dy - 1;
#pragma unroll
            for (int dx = 0; dx < 3; dx++){
                int gx = t + dx - 1;
                float v = 0.f;
                if ((unsigned)gy < 256u && (unsigned)gx < 256u)
                    v = x[ib + c*65536 + (gy<<8) + gx];
                const float* wp = &wl[c*9 + dy*3 + dx];
#pragma unroll
                for (int k = 0; k < 32; k++) acc[k] += v * wp[k*27];
            }
        }
    }
    u16 ub[32];
#pragma unroll
    for (int k = 0; k < 32; k++) ub[k] = f2bf(acc[k]);
    u16* dst = f1 + ((long)(b*65536 + (y<<8) + t)) * 32;
#pragma unroll
    for (int j = 0; j < 4; j++) *(int4*)(dst + j*8) = *(int4*)(ub + j*8);
}

// weight transpose: wt[tap][k][c] = bf16(w[k][c][tap])
__global__ __launch_bounds__(256)
void prep_w(const float* __restrict__ w, u16* __restrict__ wt, int K, int C)
{
    int i = blockIdx.x*256 + threadIdx.x;
    if (i >= 9*K*C) return;
    int c = i % C; int r = i / C; int k = r % K; int tap = r / K;
    wt[i] = f2bf(w[((long)k*C + c)*9 + tap]);
}

// ---------------------------------------------------------------------------
// BN stats over NHWC bf16 (layer 1 only)
// ---------------------------------------------------------------------------
template<int C>
__global__ __launch_bounds__(256)
void bn_stats_nhwc(const u16* __restrict__ f, float* __restrict__ part)
{
    constexpr int CQ = C/4;
    constexpr int SUBS = 256/CQ;
    const int t = threadIdx.x;
    const int cq = t & (CQ-1);
    const int sub = t / CQ;
    const long rowbase = (long)blockIdx.x * 512;
    float s[4] = {0,0,0,0}, q2[4] = {0,0,0,0};
    for (int r = sub; r < 512; r += SUBS){
        ushort4 v = *(const ushort4*)(f + (rowbase + r)*C + cq*4);
        float x0 = bf2f(v.x), x1 = bf2f(v.y), x2 = bf2f(v.z), x3 = bf2f(v.w);
        s[0]+=x0; q2[0]+=x0*x0; s[1]+=x1; q2[1]+=x1*x1;
        s[2]+=x2; q2[2]+=x2*x2; s[3]+=x3; q2[3]+=x3*x3;
    }
    __shared__ float r0[256], r1[256];
    for (int j = 0; j < 4; j++){
        r0[t] = s[j]; r1[t] = q2[j];
        __syncthreads();
        for (int st = 128; st >= CQ; st >>= 1){
            if (t < st){ r0[t] += r0[t+st]; r1[t] += r1[t+st]; }
            __syncthreads();
        }
        if (t < CQ){
            part[((long)blockIdx.x * C + t*4 + j)*2]     = r0[t];
            part[((long)blockIdx.x * C + t*4 + j)*2 + 1] = r1[t];
        }
        __syncthreads();
    }
}

__global__ __launch_bounds__(256)
void bn_stats_final2(const float* __restrict__ part, const float* __restrict__ g,
                     const float* __restrict__ bb, int C, int NB, float* __restrict__ ss)
{
    const int c = blockIdx.x, t = threadIdx.x;
    float s = 0.f, s2 = 0.f;
    for (int i = t; i < NB; i += 256){
        s  += part[((long)i*C + c)*2];
        s2 += part[((long)i*C + c)*2 + 1];
    }
    __shared__ float r0[256], r1[256];
    r0[t] = s; r1[t] = s2;
    __syncthreads();
    for (int st = 128; st > 0; st >>= 1){
        if (t < st){ r0[t] += r0[t+st]; r1[t] += r1[t+st]; }
        __syncthreads();
    }
    if (t == 0){
        const float invN = 1.f/524288.f;
        float m = r0[0]*invN;
        float v = r1[0]*invN - m*m;
        float sc = g[c]/sqrtf(v + 1e-5f);
        ss[c] = sc; ss[C+c] = bb[c] - m*sc;
    }
}

// apply BN+lrelu in place on NHWC bf16
template<int C>
__global__ __launch_bounds__(256)
void bn_apply(u16* __restrict__ f, const float* __restrict__ ss, long n8)
{
    long i = (long)blockIdx.x*256 + threadIdx.x;
    if (i >= n8) return;
    u16x8 v = *(u16x8*)(f + i*8);
    int c0 = (int)((i*8) & (C-1));
#pragma unroll
    for (int j = 0; j < 8; j++){
        float xx = bf2f(v[j]);
        xx = lrelu(ss[c0+j]*xx + ss[C+c0+j]);
        v[j] = f2bf(xx);
    }
    *(u16x8*)(f + i*8) = v;
}

// normalize + lrelu layer-4 fp32 NCHW in place
__global__ __launch_bounds__(256)
void bn_finalize(float* __restrict__ feat, const float* __restrict__ ss)
{
    const long e4 = (long)blockIdx.x*256 + threadIdx.x;
    const int c = (int)((e4 >> 14) & 255);
    const float sc = ss[c], sh = ss[256 + c];
    float4 v = reinterpret_cast<float4*>(feat)[e4];
    v.x = lrelu(sc*v.x + sh); v.y = lrelu(sc*v.y + sh);
    v.z = lrelu(sc*v.z + sh); v.w = lrelu(sc*v.w + sh);
    reinterpret_cast<float4*>(feat)[e4] = v;
}

// ---------------------------------------------------------------------------
// gathers + decoder MLP
// ---------------------------------------------------------------------------
__global__ __launch_bounds__(256)
void gather_w(const float* __restrict__ feat, const int* __restrict__ hw,
              float* __restrict__ outW)
{
    const int site = blockIdx.x;
    const int b = site >> 10;
    const int y = hw[site*2], x = hw[site*2 + 1];
    const int c = threadIdx.x;
    const long fidx = (((long)(b*256 + c)) << 16) + ((long)y << 8) + x;
    outW[(long)site*256 + c] = feat[fidx];
}

__global__ __launch_bounds__(256)
void gather_patch(const float* __restrict__ x, const int* __restrict__ hw,
                  float* __restrict__ out)
{
    const long i = (long)blockIdx.x*256 + threadIdx.x;
    if (i >= 1204224L) return;
    const int px = (int)(i % 7);
    long r = i / 7;
    const int py = (int)(r % 7); r /= 7;
    const int c  = (int)(r % 3); r /= 3;
    const int s  = (int)(r % 1024);
    const int b  = (int)(r / 1024);
    const int site = b*1024 + s;
    const int yy = hw[site*2]     - 3 + py;
    const int xx = hw[site*2 + 1] - 3 + px;
    out[i] = x[(((long)(b*3 + c)) << 16) + ((long)yy << 8) + xx];
}

__global__ __launch_bounds__(256)
void mlp(const float* __restrict__ Wa, const float* __restrict__ l1w,
         const float* __restrict__ l1b, const float* __restrict__ l2w,
         const float* __restrict__ l2b, float* __restrict__ out)
{
    __shared__ float wa[256];
    __shared__ float h[160];
    const int site = blockIdx.x;
    const int t = threadIdx.x;
    wa[t] = Wa[(long)site*256 + t];
    __syncthreads();
    if (t < PD){
        float a = l1b[t];
        const float* wr = l1w + t*256;
#pragma unroll 8
        for (int l = 0; l < 256; l++) a += wa[l]*wr[l];
        h[t] = lrelu(a);
    }
    __syncthreads();
    if (t < PD){
        float a = l2b[t];
        const float* wr = l2w + t*PD;
        for (int p = 0; p < PD; p++) a += h[p]*wr[p];
        out[(long)site*PD + t] = a;
    }
}

extern "C" void kernel_launch(void* const* d_in, const int* in_sizes, int n_in,
                              void* d_out, int out_size, void* d_ws, size_t ws_size,
                              hipStream_t stream)
{
    const float* x   = (const float*)d_in[0];
    const int*   anc = (const int*)  d_in[1];
    const int*   pos = (const int*)  d_in[2];
    const float* w1  = (const float*)d_in[3];
    const float* g1  = (const float*)d_in[4];
    const float* b1  = (const float*)d_in[5];
    const float* w2  = (const float*)d_in[6];
    const float* g2  = (const float*)d_in[7];
    const float* b2  = (const float*)d_in[8];
    const float* w3  = (const float*)d_in[9];
    const float* g3  = (const float*)d_in[10];
    const float* b3  = (const float*)d_in[11];
    const float* w4  = (const float*)d_in[12];
    const float* g4  = (const float*)d_in[13];
    const float* b4  = (const float*)d_in[14];
    const float* l1w = (const float*)d_in[15];
    const float* l1b = (const float*)d_in[16];
    const float* l2w = (const float*)d_in[17];
    const float* l2b = (const float*)d_in[18];

    float* feat = (float*)d_out;
    float* oPR  = feat + OFF_PREAL;
    float* oRC  = feat + OFF_PRECON;
    float* oWA  = feat + OFF_WA;
    float* oWP  = feat + OFF_WP;

    // ws: f2 [0,64MB), f3 [64MB,192MB), f1 [128MB,160MB) (inside f3, dead before conv3)
    char* wsb = (char*)d_ws;
    u16* f2b = (u16*)wsb;
    u16* f3b = (u16*)(wsb + 67108864L);
    u16* f1b = (u16*)(wsb + 134217728L);

    // scratch inside d_out regions only written by the final kernels
    u16* Wt2 = (u16*)oWA;
    u16* Wt3 = Wt2 + 18432;
    u16* Wt4 = Wt3 + 73728;
    float* part = oWP;                                   // 4096*256*2 floats max
    float* ss1 = oRC, *ss2 = oRC + 64, *ss3 = oRC + 192, *ss4 = oRC + 448;

    prep_w<<<72,   256, 0, stream>>>(w2, Wt2, 64, 32);
    prep_w<<<288,  256, 0, stream>>>(w3, Wt3, 128, 64);
    prep_w<<<1152, 256, 0, stream>>>(w4, Wt4, 256, 128);

    conv1_direct<<<dim3(256,8), 256, 0, stream>>>(x, w1, f1b);
    bn_stats_nhwc<32><<<1024, 256, 0, stream>>>(f1b, part);
    bn_stats_final2<<<32, 256, 0, stream>>>(part, g1, b1, 32, 1024, ss1);
    bn_apply<32><<<8192, 256, 0, stream>>>(f1b, ss1, 2097152L);

    conv_mfma<32,64,false><<<dim3(256,8), 512, 0, stream>>>(f1b, Wt2, f2b, part);
    bn_stats_final2<<<64, 256, 0, stream>>>(part, g2, b2, 64, 4096, ss2);
    bn_apply<64><<<16384, 256, 0, stream>>>(f2b, ss2, 4194304L);

    conv_mfma<64,128,false><<<dim3(256,8), 512, 0, stream>>>(f2b, Wt3, f3b, part);
    bn_stats_final2<<<128, 256, 0, stream>>>(part, g3, b3, 128, 4096, ss3);
    bn_apply<128><<<32768, 256, 0, stream>>>(f3b, ss3, 8388608L);

    conv_mfma<128,256,true><<<dim3(256,8), 512, 0, stream>>>(f3b, Wt4, feat, part);
    bn_stats_final2<<<256, 256, 0, stream>>>(part, g4, b4, 256, 4096, ss4);
    bn_finalize<<<131072, 256, 0, stream>>>(feat, ss4);

    gather_w<<<8192, 256, 0, stream>>>(feat, anc, oWA);
    gather_w<<<8192, 256, 0, stream>>>(feat, pos, oWP);
    gather_patch<<<4704, 256, 0, stream>>>(x, anc, oPR);
    mlp<<<8192, 256, 0, stream>>>(oWA, l1w, l1b, l2w, l2b, oRC);
}